// Round 5
// baseline (29.936 us; speedup 1.0000x reference)
//
#include <hip/hip_runtime.h>
#include <hip/hip_bf16.h>
#include <stdint.h>

#define Kdim 2048
#define Vdim 768
#define Mdim 4096   // B*N = 16*256

#define BMx 128
#define BNx 128
#define BKx 128
#define NTx (Vdim / BKx)   // 6 K-tiles

typedef __attribute__((ext_vector_type(4))) int  i32x4;
typedef __attribute__((ext_vector_type(16))) int i32x16;

#define CFENCE asm volatile("" ::: "memory")

__device__ __forceinline__ void gld_lds16(const void* g, void* l) {
    __builtin_amdgcn_global_load_lds((const __attribute__((address_space(1))) void*)g,
                                     (__attribute__((address_space(3))) void*)l, 16, 0, 0);
}

// One wave per row (4 rows/block):
//   rows [0, Mdim)         : inputs -> i8 Aq (per-row scale sxa) + fp32 sumsq xsq
//   rows [Mdim, Mdim+Kdim) : protos -> i8 Pq (spa) + psq + fp32 pass-through copy
__global__ __launch_bounds__(256) void rowquant(const float* __restrict__ x,
                                                const float* __restrict__ p,
                                                int8_t* __restrict__ Aq,
                                                int8_t* __restrict__ Pq,
                                                float* __restrict__ xsq,
                                                float* __restrict__ psq,
                                                float* __restrict__ sxa,
                                                float* __restrict__ spa,
                                                float* __restrict__ proto_out) {
    const int row = blockIdx.x * 4 + (threadIdx.x >> 6);
    const int lane = threadIdx.x & 63;

    const float* src;
    int8_t* dq;
    float *sq, *sc, *cpy = nullptr;
    if (row < Mdim) {
        src = x + (size_t)row * Vdim; dq = Aq + (size_t)row * Vdim;
        sq = xsq + row; sc = sxa + row;
    } else {
        const int r = row - Mdim;
        src = p + (size_t)r * Vdim; dq = Pq + (size_t)r * Vdim;
        sq = psq + r; sc = spa + r; cpy = proto_out + (size_t)r * Vdim;
    }

    float4 v[3];
    float s = 0.f, mx = 0.f;
#pragma unroll
    for (int j = 0; j < 3; ++j) {
        v[j] = *reinterpret_cast<const float4*>(src + j * 256 + lane * 4);
        s += v[j].x * v[j].x + v[j].y * v[j].y + v[j].z * v[j].z + v[j].w * v[j].w;
        mx = fmaxf(mx, fmaxf(fmaxf(fabsf(v[j].x), fabsf(v[j].y)),
                             fmaxf(fabsf(v[j].z), fabsf(v[j].w))));
        if (cpy) *reinterpret_cast<float4*>(cpy + j * 256 + lane * 4) = v[j];
    }
#pragma unroll
    for (int off = 32; off > 0; off >>= 1) {
        s += __shfl_xor(s, off);
        mx = fmaxf(mx, __shfl_xor(mx, off));
    }
    mx = fmaxf(mx, 1e-20f);
    const float inv = 127.0f / mx;
#pragma unroll
    for (int j = 0; j < 3; ++j) {
        int q0 = min(127, max(-127, __float2int_rn(v[j].x * inv)));
        int q1 = min(127, max(-127, __float2int_rn(v[j].y * inv)));
        int q2 = min(127, max(-127, __float2int_rn(v[j].z * inv)));
        int q3 = min(127, max(-127, __float2int_rn(v[j].w * inv)));
        int packed = (q0 & 0xff) | ((q1 & 0xff) << 8) | ((q2 & 0xff) << 16) | (q3 << 24);
        *reinterpret_cast<int*>(dq + j * 256 + lane * 4) = packed;
    }
    if (lane == 0) { *sq = s; *sc = mx * (1.0f / 127.0f); }
}

// i8 GEMM: 128x128 tile, BK=128, 4 waves (2x2, 64x64/wave), double-buffered
// 64KB LDS -> 2 blocks/CU (inter-block overlap = the m97 mechanism), grid 512,
// XOR-swizzled LDS (both-sides), XCD-swizzled grid, one vmcnt(0)+barrier per
// K-tile. Fused distance epilogue: xsq + psq - 2*sx*sp*acc.
__global__ __launch_bounds__(256, 2) void gemm_dist_i8(const int8_t* __restrict__ Aq,
                                                       const int8_t* __restrict__ Pq,
                                                       const float* __restrict__ xsq,
                                                       const float* __restrict__ psq,
                                                       const float* __restrict__ sxa,
                                                       const float* __restrict__ spa,
                                                       float* __restrict__ out) {
    __shared__ int8_t As[2][BMx * BKx];   // 2 x 16KB
    __shared__ int8_t Bs[2][BNx * BKx];   // 2 x 16KB

    const int t = threadIdx.x;
    const int lane = t & 63;
    const int wave = t >> 6;       // 0..3
    const int wr = wave >> 1;      // 0..1 (M)
    const int wc = wave & 1;       // 0..1 (N)
    const int ln31 = lane & 31;
    const int lh = lane >> 5;      // 0..1

    // T1: bijective XCD swizzle (512 blocks % 8 == 0)
    const int wg = (blockIdx.x & 7) * 64 + (blockIdx.x >> 3);
    const int bm = wg >> 4;        // 0..31
    const int bn = wg & 15;        // 0..15
    const int m0 = bm * BMx, n0 = bn * BNx;

    // Staging: linear LDS dest (gld_lds requirement), inverse-swizzled global
    // source. Issue q covers rows q*32..q*32+31: thread t -> row q*32+(t>>3),
    // physical 16B-slot t&7 which holds logical 16B-col (t&7)^(row&7).
    const int srow = t >> 3;                        // 0..31
    const int scol = ((t & 7) ^ (srow & 7)) * 16;   // i8 elements
    const int8_t* Ag = Aq + (size_t)(m0 + srow) * Vdim + scol;
    const int8_t* Bg = Pq + (size_t)(n0 + srow) * Vdim + scol;
    const int ldsoff = wave * 1024;                 // wave's 1KB slice of a 4KB issue

    // Swizzled ds_read byte offsets: row r, logical 16B-col k16 -> slot k16^(r&7).
    int offA[2][4], offB[2][4];
#pragma unroll
    for (int mt = 0; mt < 2; ++mt)
#pragma unroll
        for (int ks = 0; ks < 4; ++ks) {
            const int k16 = ks * 2 + lh;
            const int rA = wr * 64 + mt * 32 + ln31;
            const int rB = wc * 64 + mt * 32 + ln31;
            offA[mt][ks] = rA * BKx + ((k16 ^ (rA & 7)) * 16);
            offB[mt][ks] = rB * BKx + ((k16 ^ (rB & 7)) * 16);
        }

    auto stage = [&](int buf, int kt) {
#pragma unroll
        for (int q = 0; q < 4; ++q)
            gld_lds16(Ag + (size_t)q * 32 * Vdim + kt * BKx, (void*)(&As[buf][q * 4096 + ldsoff]));
#pragma unroll
        for (int q = 0; q < 4; ++q)
            gld_lds16(Bg + (size_t)q * 32 * Vdim + kt * BKx, (void*)(&Bs[buf][q * 4096 + ldsoff]));
    };

    i32x16 acc[2][2] = {};

    stage(0, 0);
    asm volatile("s_waitcnt vmcnt(0)" ::: "memory");
    __builtin_amdgcn_s_barrier();
    CFENCE;

    int cur = 0;
    for (int kt = 0; kt < NTx; ++kt) {
        if (kt + 1 < NTx) stage(cur ^ 1, kt + 1);   // issue prefetch FIRST

        const int8_t* Ap = &As[cur][0];
        const int8_t* Bp = &Bs[cur][0];
        i32x4 af[2][4], bf[2][4];
#pragma unroll
        for (int mt = 0; mt < 2; ++mt)
#pragma unroll
            for (int ks = 0; ks < 4; ++ks) {
                af[mt][ks] = *reinterpret_cast<const i32x4*>(Ap + offA[mt][ks]);
                bf[mt][ks] = *reinterpret_cast<const i32x4*>(Bp + offB[mt][ks]);
            }
        CFENCE;
        __builtin_amdgcn_s_setprio(1);
#pragma unroll
        for (int ks = 0; ks < 4; ++ks)
#pragma unroll
            for (int mt = 0; mt < 2; ++mt)
#pragma unroll
                for (int nt = 0; nt < 2; ++nt)
                    acc[mt][nt] = __builtin_amdgcn_mfma_i32_32x32x32_i8(af[mt][ks], bf[nt][ks], acc[mt][nt], 0, 0, 0);
        __builtin_amdgcn_s_setprio(0);
        CFENCE;
        asm volatile("s_waitcnt vmcnt(0)" ::: "memory");   // prefetch landed block-wide
        __builtin_amdgcn_s_barrier();
        CFENCE;
        cur ^= 1;
    }

    // Epilogue. 32x32 C/D layout: col=lane&31, row=(reg&3)+8*(reg>>2)+4*(lane>>5).
    float ps_[2], sp_[2];
    int col_[2];
#pragma unroll
    for (int nt = 0; nt < 2; ++nt) {
        col_[nt] = n0 + wc * 64 + nt * 32 + ln31;
        ps_[nt] = psq[col_[nt]];
        sp_[nt] = spa[col_[nt]];
    }
#pragma unroll
    for (int mt = 0; mt < 2; ++mt)
#pragma unroll
        for (int reg = 0; reg < 16; ++reg) {
            const int row = m0 + wr * 64 + mt * 32 + (reg & 3) + 8 * (reg >> 2) + 4 * lh;
            const float xs = xsq[row];
            const float m2sx = -2.0f * sxa[row];
#pragma unroll
            for (int nt = 0; nt < 2; ++nt)
                out[(size_t)row * Kdim + col_[nt]] =
                    xs + ps_[nt] + m2sx * sp_[nt] * (float)acc[mt][nt][reg];
        }
}

extern "C" void kernel_launch(void* const* d_in, const int* in_sizes, int n_in,
                              void* d_out, int out_size, void* d_ws, size_t ws_size,
                              hipStream_t stream) {
    const float* x = (const float*)d_in[0];   // (16,256,768) fp32
    const float* p = (const float*)d_in[1];   // (2048,768) fp32
    float* out = (float*)d_out;               // distances (4096x2048) + prototypes (2048x768)

    char* ws = (char*)d_ws;
    int8_t* Aq = (int8_t*)ws;                          // 3,145,728 B
    int8_t* Pq = (int8_t*)(ws + 3145728);              // 1,572,864 B
    float* xsq = (float*)(ws + 4718592);               // 16,384 B
    float* psq = (float*)(ws + 4734976);               // 8,192 B
    float* sxa = (float*)(ws + 4743168);               // 16,384 B
    float* spa = (float*)(ws + 4759552);               // 8,192 B

    rowquant<<<(Mdim + Kdim) / 4, 256, 0, stream>>>(x, p, Aq, Pq, xsq, psq, sxa, spa,
                                                    out + (size_t)Mdim * Kdim);
    gemm_dist_i8<<<(Mdim / BMx) * (Kdim / BNx), 256, 0, stream>>>(Aq, Pq, xsq, psq, sxa, spa, out);
}

// Round 6
// 28.484 us; speedup vs baseline: 1.0510x; 1.0510x over previous
//
#include <hip/hip_runtime.h>
#include <hip/hip_bf16.h>
#include <stdint.h>

#define Kdim 2048
#define Vdim 768
#define Mdim 4096   // B*N = 16*256

#define BMx 128
#define BNx 128
#define BKx 64
#define NTx (Vdim / BKx)   // 12 K-steps

typedef __attribute__((ext_vector_type(4))) int  i32x4;
typedef __attribute__((ext_vector_type(16))) int i32x16;

#define CFENCE asm volatile("" ::: "memory")

__device__ __forceinline__ void gld_lds16(const void* g, void* l) {
    __builtin_amdgcn_global_load_lds((const __attribute__((address_space(1))) void*)g,
                                     (__attribute__((address_space(3))) void*)l, 16, 0, 0);
}

// One wave per row (4 rows/block):
//   rows [0, Mdim)         : inputs -> i8 Aq (per-row scale sxa) + fp32 sumsq xsq
//   rows [Mdim, Mdim+Kdim) : protos -> i8 Pq (spa) + psq   (fp32 copy moved to GEMM)
__global__ __launch_bounds__(256) void rowquant(const float* __restrict__ x,
                                                const float* __restrict__ p,
                                                int8_t* __restrict__ Aq,
                                                int8_t* __restrict__ Pq,
                                                float* __restrict__ xsq,
                                                float* __restrict__ psq,
                                                float* __restrict__ sxa,
                                                float* __restrict__ spa) {
    const int row = blockIdx.x * 4 + (threadIdx.x >> 6);
    const int lane = threadIdx.x & 63;

    const float* src;
    int8_t* dq;
    float *sq, *sc;
    if (row < Mdim) {
        src = x + (size_t)row * Vdim; dq = Aq + (size_t)row * Vdim;
        sq = xsq + row; sc = sxa + row;
    } else {
        const int r = row - Mdim;
        src = p + (size_t)r * Vdim; dq = Pq + (size_t)r * Vdim;
        sq = psq + r; sc = spa + r;
    }

    float4 v[3];
    float s = 0.f, mx = 0.f;
#pragma unroll
    for (int j = 0; j < 3; ++j) {
        v[j] = *reinterpret_cast<const float4*>(src + j * 256 + lane * 4);
        s += v[j].x * v[j].x + v[j].y * v[j].y + v[j].z * v[j].z + v[j].w * v[j].w;
        mx = fmaxf(mx, fmaxf(fmaxf(fabsf(v[j].x), fabsf(v[j].y)),
                             fmaxf(fabsf(v[j].z), fabsf(v[j].w))));
    }
#pragma unroll
    for (int off = 32; off > 0; off >>= 1) {
        s += __shfl_xor(s, off);
        mx = fmaxf(mx, __shfl_xor(mx, off));
    }
    mx = fmaxf(mx, 1e-20f);
    const float inv = 127.0f / mx;
#pragma unroll
    for (int j = 0; j < 3; ++j) {
        int q0 = min(127, max(-127, __float2int_rn(v[j].x * inv)));
        int q1 = min(127, max(-127, __float2int_rn(v[j].y * inv)));
        int q2 = min(127, max(-127, __float2int_rn(v[j].z * inv)));
        int q3 = min(127, max(-127, __float2int_rn(v[j].w * inv)));
        int packed = (q0 & 0xff) | ((q1 & 0xff) << 8) | ((q2 & 0xff) << 16) | (q3 << 24);
        *reinterpret_cast<int*>(dq + j * 256 + lane * 4) = packed;
    }
    if (lane == 0) { *sq = s; *sc = mx * (1.0f / 127.0f); }
}

// i8 GEMM: 128x128 tile, BK=64, 4 waves (2x2, 64x64/wave), TRIPLE-buffered
// 48KB LDS -> 2 blocks/CU, counted vmcnt(4) (tile-after-next stays in flight
// across the barrier), one barrier per K-step, XOR swizzle for 64B rows
// (slot ^= (row>>1)&3, both-sides), XCD-swizzled grid. Fused distance
// epilogue + proto fp32 pass-through copy.
__global__ __launch_bounds__(256, 2) void gemm_dist_i8(const int8_t* __restrict__ Aq,
                                                       const int8_t* __restrict__ Pq,
                                                       const float* __restrict__ xsq,
                                                       const float* __restrict__ psq,
                                                       const float* __restrict__ sxa,
                                                       const float* __restrict__ spa,
                                                       const float* __restrict__ p,
                                                       float* __restrict__ out) {
    __shared__ int8_t As[3][BMx * BKx];   // 3 x 8KB
    __shared__ int8_t Bs[3][BNx * BKx];   // 3 x 8KB

    const int t = threadIdx.x;
    const int lane = t & 63;
    const int wave = t >> 6;       // 0..3
    const int wr = wave >> 1;      // 0..1 (M)
    const int wc = wave & 1;       // 0..1 (N)
    const int ln31 = lane & 31;
    const int lh = lane >> 5;      // 0..1

    // T1: bijective XCD swizzle (512 blocks % 8 == 0)
    const int wg = (blockIdx.x & 7) * 64 + (blockIdx.x >> 3);
    const int bm = wg >> 4;        // 0..31
    const int bn = wg & 15;        // 0..15
    const int m0 = bm * BMx, n0 = bn * BNx;

    // Staging: linear LDS dest (gld_lds writes base + lane*16), inverse-swizzled
    // global source. One block-wide issue = 4KB = 64 rows x 64B; thread t ->
    // row t>>2, phys 16B-slot t&3, sourcing logical slot (t&3) ^ ((row>>1)&3).
    const int srow = t >> 2;                               // 0..63
    const int scol = ((t & 3) ^ ((srow >> 1) & 3)) * 16;   // i8 elements
    const int8_t* Ag = Aq + (size_t)(m0 + srow) * Vdim + scol;
    const int8_t* Bg = Pq + (size_t)(n0 + srow) * Vdim + scol;
    const int ldsoff = wave * 1024;                        // wave slice of a 4KB issue

    // Swizzled ds_read byte offsets: row r, logical 16B-slot S -> phys S^((r>>1)&3).
    // Frag for (mt, ks): row = w?*64 + mt*32 + ln31, S = ks*2 + lh.
    int offA[2][2], offB[2][2];
#pragma unroll
    for (int mt = 0; mt < 2; ++mt)
#pragma unroll
        for (int ks = 0; ks < 2; ++ks) {
            const int S = ks * 2 + lh;
            const int rA = wr * 64 + mt * 32 + ln31;
            const int rB = wc * 64 + mt * 32 + ln31;
            offA[mt][ks] = rA * BKx + ((S ^ ((rA >> 1) & 3)) * 16);
            offB[mt][ks] = rB * BKx + ((S ^ ((rB >> 1) & 3)) * 16);
        }

    // Stage K-step kt into buffer buf: 2 block-wide issues for A, 2 for B
    // (4 vmem instructions per wave).
    auto stage = [&](int buf, int kt) {
#pragma unroll
        for (int q = 0; q < 2; ++q)
            gld_lds16(Ag + (size_t)q * 64 * Vdim + kt * BKx, (void*)(&As[buf][q * 4096 + ldsoff]));
#pragma unroll
        for (int q = 0; q < 2; ++q)
            gld_lds16(Bg + (size_t)q * 64 * Vdim + kt * BKx, (void*)(&Bs[buf][q * 4096 + ldsoff]));
    };

    i32x16 acc[2][2] = {};

    // Prologue: stage K-steps 0,1,2 (12 instrs/wave); wait step 0 (8 in flight).
    stage(0, 0); stage(1, 1); stage(2, 2);
    asm volatile("s_waitcnt vmcnt(8)" ::: "memory");
    __builtin_amdgcn_s_barrier();
    CFENCE;

    int cb = 0, cs = 0;   // compute buf = kt%3; stage target = (kt+2)%3
    for (int kt = 0; kt < NTx; ++kt) {
        if (kt + 2 < NTx) {
            cs = cb + 2; if (cs >= 3) cs -= 3;
            stage(cs, kt + 2);             // issue prefetch FIRST (T3 recipe)
        }

        const int8_t* Ap = &As[cb][0];
        const int8_t* Bp = &Bs[cb][0];
        i32x4 af[2][2], bf[2][2];
#pragma unroll
        for (int mt = 0; mt < 2; ++mt)
#pragma unroll
            for (int ks = 0; ks < 2; ++ks) {
                af[mt][ks] = *reinterpret_cast<const i32x4*>(Ap + offA[mt][ks]);
                bf[mt][ks] = *reinterpret_cast<const i32x4*>(Bp + offB[mt][ks]);
            }
        CFENCE;
        __builtin_amdgcn_s_setprio(1);
#pragma unroll
        for (int ks = 0; ks < 2; ++ks)
#pragma unroll
            for (int mt = 0; mt < 2; ++mt)
#pragma unroll
                for (int nt = 0; nt < 2; ++nt)
                    acc[mt][nt] = __builtin_amdgcn_mfma_i32_32x32x32_i8(af[mt][ks], bf[nt][ks], acc[mt][nt], 0, 0, 0);
        __builtin_amdgcn_s_setprio(0);
        CFENCE;
        // Counted wait: K-step kt+1 must have landed; kt+2's 4 issues stay in flight.
        if (kt + 2 < NTx)       asm volatile("s_waitcnt vmcnt(4)" ::: "memory");
        else if (kt + 2 == NTx) asm volatile("s_waitcnt vmcnt(0)" ::: "memory");
        if (kt + 1 < NTx) { __builtin_amdgcn_s_barrier(); CFENCE; }
        cb = cb + 1; if (cb >= 3) cb -= 3;
    }

    // Proto fp32 pass-through: 512 blocks x 3072 floats (12KB) each.
    {
        const float* srcp = p + (size_t)blockIdx.x * 3072;
        float* dstp = out + (size_t)Mdim * Kdim + (size_t)blockIdx.x * 3072;
#pragma unroll
        for (int j = 0; j < 3; ++j)
            *reinterpret_cast<float4*>(dstp + j * 1024 + t * 4) =
                *reinterpret_cast<const float4*>(srcp + j * 1024 + t * 4);
    }

    // Epilogue. 32x32 C/D layout: col=lane&31, row=(reg&3)+8*(reg>>2)+4*(lane>>5).
    float ps_[2], sp_[2];
    int col_[2];
#pragma unroll
    for (int nt = 0; nt < 2; ++nt) {
        col_[nt] = n0 + wc * 64 + nt * 32 + ln31;
        ps_[nt] = psq[col_[nt]];
        sp_[nt] = spa[col_[nt]];
    }
#pragma unroll
    for (int mt = 0; mt < 2; ++mt)
#pragma unroll
        for (int reg = 0; reg < 16; ++reg) {
            const int row = m0 + wr * 64 + mt * 32 + (reg & 3) + 8 * (reg >> 2) + 4 * lh;
            const float xs = xsq[row];
            const float m2sx = -2.0f * sxa[row];
#pragma unroll
            for (int nt = 0; nt < 2; ++nt)
                out[(size_t)row * Kdim + col_[nt]] =
                    xs + ps_[nt] + m2sx * sp_[nt] * (float)acc[mt][nt][reg];
        }
}

extern "C" void kernel_launch(void* const* d_in, const int* in_sizes, int n_in,
                              void* d_out, int out_size, void* d_ws, size_t ws_size,
                              hipStream_t stream) {
    const float* x = (const float*)d_in[0];   // (16,256,768) fp32
    const float* p = (const float*)d_in[1];   // (2048,768) fp32
    float* out = (float*)d_out;               // distances (4096x2048) + prototypes (2048x768)

    char* ws = (char*)d_ws;
    int8_t* Aq = (int8_t*)ws;                          // 3,145,728 B
    int8_t* Pq = (int8_t*)(ws + 3145728);              // 1,572,864 B
    float* xsq = (float*)(ws + 4718592);               // 16,384 B
    float* psq = (float*)(ws + 4734976);               // 8,192 B
    float* sxa = (float*)(ws + 4743168);               // 16,384 B
    float* spa = (float*)(ws + 4759552);               // 8,192 B

    rowquant<<<(Mdim + Kdim) / 4, 256, 0, stream>>>(x, p, Aq, Pq, xsq, psq, sxa, spa);
    gemm_dist_i8<<<(Mdim / BMx) * (Kdim / BNx), 256, 0, stream>>>(Aq, Pq, xsq, psq, sxa, spa,
                                                                  p, out);
}